// Round 4
// baseline (217.912 us; speedup 1.0000x reference)
//
#include <hip/hip_runtime.h>
#include <float.h>

// VectorQuantizer on MI355X — bit-exact replication of the numpy-f32 reference.
//
// The checker's reference ("ref=np") computes, in float32:
//   t1[n] = np.sum(flat*flat, axis=1)   (pairwise 8-accumulator tree)
//   t2[k] = np.sum(emb*emb, axis=1)     (same tree)
//   d[n,k] = sgemm(flat, emb.T)         (sequential-k FMA chain)
//   dist  = fl32( fl32(t1 + t2) - 2*d ) ; idx = first-argmin
// The distances are ~64 (the ||x||^2 term dominates), quantized at ulp(64)=7.6e-6,
// while best-vs-2nd gaps are ~4.5e-3 — so ~0.2% of pixels are decided by f32
// ROUNDING, not math. Being "more accurate" (R2's fp64 rescue: absmax unchanged
// at 323 == falsified) cannot pass; only bit-exact replication can.
//
// File-scope contract(off): plain * and + round separately (numpy semantics);
// explicit fmaf() stays fused (BLAS chain + final X-2d single rounding).
#pragma clang fp contract(off)

#define K_EMB   512
#define D_EMB   64
#define Q_ELEMS 4194304   // 64 * 64 * 32 * 32

// numpy pairwise_sum order for n=64 contiguous f32, summing PRE-ROUNDED squares.
// r[j] = ((sq[j]+sq[j+8])+sq[j+16])+...+sq[j+56]; then the fixed combine tree.
__device__ __forceinline__ float np_sumsq64(const float* __restrict__ v) {
    float r[8];
    #pragma unroll
    for (int j = 0; j < 8; ++j) r[j] = v[j] * v[j];
    #pragma unroll
    for (int i = 8; i < 64; i += 8) {
        #pragma unroll
        for (int j = 0; j < 8; ++j) {
            float s = v[i + j] * v[i + j];
            r[j] = r[j] + s;
        }
    }
    return ((r[0] + r[1]) + (r[2] + r[3])) + ((r[4] + r[5]) + (r[6] + r[7]));
}

// ---------------- kernel 1: t2[k] = np-f32 sum(emb_k^2) ----------------
__global__ __launch_bounds__(256) void vq_prep(const float* __restrict__ emb,
                                               float* __restrict__ t2) {
    int k = blockIdx.x * 256 + threadIdx.x;
    if (k < K_EMB) {
        float e[D_EMB];
        const float* ep = emb + (k << 6);
        #pragma unroll
        for (int j = 0; j < D_EMB; ++j) e[j] = ep[j];
        t2[k] = np_sumsq64(e);
    }
}

// ---------------- kernel 2: main VQ ----------------
__global__ __launch_bounds__(256) void vq_main(const float* __restrict__ x,
                                               const float* __restrict__ emb,
                                               const float* __restrict__ t2,
                                               float* __restrict__ out_q,
                                               float* __restrict__ out_idx,
                                               float* __restrict__ partial) {
    const int n  = blockIdx.x * 256 + threadIdx.x;   // pixel index
    const int b  = n >> 10;
    const int hw = n & 1023;
    const float* __restrict__ xp = x + b * 65536 + hw;

    // x[n, 0..63] into registers (coalesced per-d across lanes)
    float xv[D_EMB];
    #pragma unroll
    for (int d = 0; d < D_EMB; ++d) xv[d] = xp[d * 1024];

    const float t1 = np_sumsq64(xv);   // numpy tree, f32

    float best = FLT_MAX;
    int   bi   = 0;
    // k-loop: 4 interleaved sequential FMA chains (BLAS microkernel order:
    // single accumulator per (n,k), ascending k-dim, one fma rounding per step).
    for (int k = 0; k < K_EMB; k += 4) {
        const float* __restrict__ e0 = emb + ((k + 0) << 6);
        const float* __restrict__ e1 = emb + ((k + 1) << 6);
        const float* __restrict__ e2 = emb + ((k + 2) << 6);
        const float* __restrict__ e3 = emb + ((k + 3) << 6);
        float a0 = 0.f, a1 = 0.f, a2 = 0.f, a3 = 0.f;
        #pragma unroll
        for (int d = 0; d < D_EMB; ++d) {
            a0 = fmaf(xv[d], e0[d], a0);
            a1 = fmaf(xv[d], e1[d], a1);
            a2 = fmaf(xv[d], e2[d], a2);
            a3 = fmaf(xv[d], e3[d], a3);
        }
        // dist = fl32( fl32(t1+t2) - 2*d ): 2*d is exact, so the fused
        // fmaf(-2,d,X) performs the identical single rounding.
        float X0 = t1 + t2[k + 0];
        float X1 = t1 + t2[k + 1];
        float X2 = t1 + t2[k + 2];
        float X3 = t1 + t2[k + 3];
        float d0 = fmaf(-2.f, a0, X0);
        float d1 = fmaf(-2.f, a1, X1);
        float d2 = fmaf(-2.f, a2, X2);
        float d3 = fmaf(-2.f, a3, X3);
        // strict < ascending k == numpy first-argmin tiebreak
        if (d0 < best) { best = d0; bi = k + 0; }
        if (d1 < best) { best = d1; bi = k + 1; }
        if (d2 < best) { best = d2; bi = k + 2; }
        if (d3 < best) { best = d3; bi = k + 3; }
    }

    // epilogue: gather winning embedding, write quantized, accumulate loss
    const float4* __restrict__ eq = (const float4*)(emb + (bi << 6));
    float* __restrict__ qp = out_q + b * 65536 + hw;
    float acc = 0.f;
    #pragma unroll
    for (int j = 0; j < 16; ++j) {
        float4 q = eq[j];
        const int d = j * 4;
        float f0 = q.x - xv[d + 0];
        float f1 = q.y - xv[d + 1];
        float f2 = q.z - xv[d + 2];
        float f3 = q.w - xv[d + 3];
        acc = fmaf(f0, f0, acc);
        acc = fmaf(f1, f1, acc);
        acc = fmaf(f2, f2, acc);
        acc = fmaf(f3, f3, acc);
        qp[(d + 0) * 1024] = q.x;
        qp[(d + 1) * 1024] = q.y;
        qp[(d + 2) * 1024] = q.z;
        qp[(d + 3) * 1024] = q.w;
    }
    out_idx[n] = (float)bi;

    // block loss partial: wave shuffle reduce, then LDS across 4 waves
    #pragma unroll
    for (int off = 32; off > 0; off >>= 1) acc += __shfl_down(acc, off);
    __shared__ float red[4];
    if ((threadIdx.x & 63) == 0) red[threadIdx.x >> 6] = acc;
    __syncthreads();
    if (threadIdx.x == 0)
        partial[blockIdx.x] = (red[0] + red[1]) + (red[2] + red[3]);
}

// ---------------- kernel 3: finalize loss ----------------
__global__ __launch_bounds__(256) void vq_loss(const float* __restrict__ partial,
                                               float* __restrict__ loss) {
    float v = partial[threadIdx.x];
    #pragma unroll
    for (int off = 32; off > 0; off >>= 1) v += __shfl_down(v, off);
    __shared__ float red[4];
    if ((threadIdx.x & 63) == 0) red[threadIdx.x >> 6] = v;
    __syncthreads();
    if (threadIdx.x == 0)
        loss[0] = 1.25f * ((red[0] + red[1]) + (red[2] + red[3])) / (float)Q_ELEMS;
}

extern "C" void kernel_launch(void* const* d_in, const int* in_sizes, int n_in,
                              void* d_out, int out_size, void* d_ws, size_t ws_size,
                              hipStream_t stream) {
    const float* x   = (const float*)d_in[0];   // [64,64,32,32] NCHW
    const float* emb = (const float*)d_in[1];   // [512,64]

    float* out_q    = (float*)d_out;                // [4194304]
    float* out_loss = (float*)d_out + Q_ELEMS;      // [1]
    float* out_idx  = (float*)d_out + Q_ELEMS + 1;  // [65536] as float

    float* t2      = (float*)d_ws;       // 512 floats
    float* partial = t2 + K_EMB;         // 256 floats

    vq_prep<<<2, 256, 0, stream>>>(emb, t2);
    vq_main<<<256, 256, 0, stream>>>(x, emb, t2, out_q, out_idx, partial);
    vq_loss<<<1, 256, 0, stream>>>(partial, out_loss);
}